// Round 9
// baseline (64.871 us; speedup 1.0000x reference)
//
#include <hip/hip_runtime.h>
#include <math.h>

#define NBS 2
#define NPTS 4096
#define HH 64
#define WW 192
#define HW (HH*WW)        // 12288
#define NC 64
#define GX 24             // cells in x (8 px each)
#define GY 8              // cells in y
#define NCELL (GX*GY)     // 192
#define CAP 416           // staged-window capacity (mean ~190, +16 sigma)

#define FBIG 3.0e38f
#define IBIG 0x7FFFFFFF

// ---------------- K0: bin points (blocks 0-1) + transpose feat_3d -----------
__global__ __launch_bounds__(256) void k0_prep(
    const float* __restrict__ uv, const float* __restrict__ f3d,
    float* __restrict__ f3dT, float4* __restrict__ binned,
    int* __restrict__ cellStart) {
#pragma clang fp contract(off)
  int bid = blockIdx.x;
  int t = threadIdx.x;
  if (bid < 2) {
    // counting-sort bin for batch b (single block per batch)
    int b = bid;
    __shared__ int hist[NCELL + 1];
    __shared__ int cur[NCELL];
    if (t <= NCELL) hist[t] = 0;
    __syncthreads();
    const float* u0p = uv + (size_t)b * 2 * NPTS;
    const float* u1p = u0p + NPTS;
    for (int n = t; n < NPTS; n += 256) {
      float u0 = u0p[n], u1 = u1p[n];
      int cxp = min((int)(u0 * 0.125f), GX - 1);   // *0.125f exact (pow2)
      int cyp = min((int)(u1 * 0.125f), GY - 1);
      atomicAdd(&hist[cyp * GX + cxp + 1], 1);
    }
    __syncthreads();
    // parallel Hillis-Steele inclusive scan over hist[0..NCELL]
    for (int off = 1; off <= NCELL; off <<= 1) {
      int v = 0;
      if (t <= NCELL && t >= off) v = hist[t - off];
      __syncthreads();
      if (t <= NCELL && t >= off) hist[t] += v;
      __syncthreads();
    }
    if (t < NCELL) cur[t] = hist[t];
    if (t <= NCELL) cellStart[b * 200 + t] = hist[t];
    __syncthreads();
    for (int n = t; n < NPTS; n += 256) {
      float u0 = u0p[n], u1 = u1p[n];
      // golden rounding: uu = rnd(rnd(u0^2)+rnd(u1^2)); contract(off) => no fma
      float s0 = u0 * u0;
      float s1 = u1 * u1;
      float uu = s0 + s1;
      int cxp = min((int)(u0 * 0.125f), GX - 1);
      int cyp = min((int)(u1 * 0.125f), GY - 1);
      int pos = atomicAdd(&cur[cyp * GX + cxp], 1);
      binned[(size_t)b * NPTS + pos] =
          make_float4(u0 + u0, u1 + u1, uu, __int_as_float(n));
    }
  } else {
    // transpose 64n x 64c tile: bid-2 in [0,128)
    int bb = bid - 2;
    int b = bb >> 6;
    int nt = (bb & 63) << 6;
    __shared__ float tile[64][65];
    int n_in = t & 63;
    int r0 = t >> 6;                       // 0..3
    const float* src = f3d + (size_t)b * NC * NPTS;
#pragma unroll
    for (int r = 0; r < 16; ++r) {
      int c = r0 + (r << 2);
      tile[c][n_in] = src[(size_t)c * NPTS + nt + n_in];
    }
    __syncthreads();
    float* dst = f3dT + ((size_t)b * NPTS + nt) * NC;
    int c_out = t & 63;
#pragma unroll
    for (int r = 0; r < 16; ++r) {
      int n = r0 + (r << 2);
      dst[(size_t)n * NC + c_out] = tile[c_out][n];
    }
  }
}

// ---------------- K1: tile-wave 3-NN -----------------------------------------
// Block = 128 threads = 2 waves, one 8x8-pixel cell per block, 1 query/lane.
// 3x3 cell window staged once in LDS; both waves scan half the list each
// (wave-uniform ds_read -> broadcast), lex (d,idx) smallest-3 per lane
// (order-independent == stable lax.top_k set), cross-wave merge via LDS.
__global__ __launch_bounds__(128) void k1_knn(
    const float4* __restrict__ binned, const int* __restrict__ cellStart,
    int4* __restrict__ idxOut) {
#pragma clang fp contract(off)
  int t = threadIdx.x;
  int lane = t & 63;
  int w = t >> 6;                    // wave 0..1
  int ci = blockIdx.x;               // cell id
  int b = blockIdx.y;
  int cx = ci % GX, cy = ci / GX;
  int x = cx * 8 + (lane & 7);
  int y = cy * 8 + (lane >> 3);
  float xf = (float)x, yf = (float)y;
  float gg = xf * xf + yf * yf;      // exact small ints

  const float4* __restrict__ pts = binned + (size_t)b * NPTS;
  const int* __restrict__ cs = cellStart + b * 200;

  int cxL = max(cx - 1, 0), cxH = min(cx + 1, GX - 1);
  int cyL = max(cy - 1, 0), cyH = min(cy + 1, GY - 1);

  __shared__ float4 spts[CAP];       // 6656 B
  __shared__ float mvv[3][64];
  __shared__ int mii[3][64];

  // window segments (one contiguous bin range per cell row)
  int nrows = cyH - cyL + 1;
  int segS[3]; int pre[4];
  pre[0] = 0;
#pragma unroll
  for (int r = 0; r < 3; ++r) {
    if (r < nrows) {
      int s = cs[(cyL + r) * GX + cxL];
      int e = cs[(cyL + r) * GX + cxH + 1];
      segS[r] = s; pre[r + 1] = pre[r] + (e - s);
    } else { segS[r] = 0; pre[r + 1] = pre[r]; }
  }
  int L = pre[3];
  bool staged = (L <= CAP);

  if (staged) {
    for (int k = t; k < L; k += 128) {
      int r = (k >= pre[1]) + (k >= pre[2]);
      spts[k] = pts[segS[r] + (k - pre[r])];
    }
  }
  __syncthreads();

  float v0 = FBIG, v1 = FBIG, v2 = FBIG;
  int i0 = IBIG, i1 = IBIG, i2 = IBIG;
  auto ins = [&](float d, int gi) {
    bool lt2 = (d < v2) || (d == v2 && gi < i2);
    bool lt1 = (d < v1) || (d == v1 && gi < i1);
    bool lt0 = (d < v0) || (d == v0 && gi < i0);
    i2 = lt1 ? i1 : (lt2 ? gi : i2);
    v2 = lt1 ? v1 : (lt2 ? d : v2);
    i1 = lt0 ? i0 : (lt1 ? gi : i1);
    v1 = lt0 ? v0 : (lt1 ? d : v1);
    i0 = lt0 ? gi : i0;
    v0 = lt0 ? d : v0;
  };

  if (staged) {
    int half = (L + 1) >> 1;
    int kB = w ? half : 0;
    int kE = w ? L : half;
#pragma unroll 2
    for (int k = kB; k < kE; ++k) {
      float4 p = spts[k];            // wave-uniform addr -> LDS broadcast
      // golden: d2 = rnd(gg+uu) - 2*fma(y,u1, rnd(x*u0)); x2 pre-scaled exact
      float d = (gg + p.z) - __builtin_fmaf(yf, p.y, xf * p.x);
      ins(d, __float_as_int(p.w));
    }
  } else {
    // rare overflow: direct global scan, waves interleave by parity
    for (int r = 0; r < nrows; ++r) {
      int len = pre[r + 1] - pre[r];
      for (int k = w; k < len; k += 2) {
        float4 p = pts[segS[r] + k];
        float d = (gg + p.z) - __builtin_fmaf(yf, p.y, xf * p.x);
        ins(d, __float_as_int(p.w));
      }
    }
  }

  if (w == 1) {
    mvv[0][lane] = v0; mii[0][lane] = i0;
    mvv[1][lane] = v1; mii[1][lane] = i1;
    mvv[2][lane] = v2; mii[2][lane] = i2;
  }
  __syncthreads();

  if (w == 0) {
    ins(mvv[0][lane], mii[0][lane]);
    ins(mvv[1][lane], mii[1][lane]);
    ins(mvv[2][lane], mii[2][lane]);

    // ring expansion (global): statistically never taken (interior dmin>=8 =>
    // dmin^2-4 >= 60 >> typical r3^2 ~ 3) but guarantees exactness, incl.
    // rounded-d2 skew (<=0.02) and staged-overflow pathologies.
    auto scanG = [&](int ry, int cA, int cB) {
      int s = cs[ry * GX + cA];
      int e = cs[ry * GX + cB + 1];
      for (int n = s; n < e; ++n) {
        float4 p = pts[n];
        float d = (gg + p.z) - __builtin_fmaf(yf, p.y, xf * p.x);
        ins(d, __float_as_int(p.w));
      }
    };
    while (true) {
      bool fullDom = (cxL == 0 && cxH == GX - 1 && cyL == 0 && cyH == GY - 1);
      float dL = (cxL > 0) ? (xf - (float)(cxL * 8)) : FBIG;
      float dR = (cxH < GX - 1) ? ((float)((cxH + 1) * 8) - xf) : FBIG;
      float dB = (cyL > 0) ? (yf - (float)(cyL * 8)) : FBIG;
      float dT = (cyH < GY - 1) ? ((float)((cyH + 1) * 8) - yf) : FBIG;
      float dmin = fminf(fminf(dL, dR), fminf(dB, dT));
      bool ok = (v2 < dmin * dmin - 4.0f);
      if (fullDom || __all(ok)) break;
      int nxL = max(cxL - 1, 0), nxH = min(cxH + 1, GX - 1);
      int nyL = max(cyL - 1, 0), nyH = min(cyH + 1, GY - 1);
      for (int ry = nyL; ry <= nyH; ++ry) {
        if (ry < cyL || ry > cyH) scanG(ry, nxL, nxH);
        else {
          if (nxL < cxL) scanG(ry, nxL, cxL - 1);
          if (nxH > cxH) scanG(ry, cxH + 1, nxH);
        }
      }
      cxL = nxL; cxH = nxH; cyL = nyL; cyH = nyH;
    }

    idxOut[(size_t)b * HW + y * WW + x] = make_int4(i0, i1, i2, 0);
  }
}

// ---------------- K2: MLP + weighted sum + out-projection -------------------
// Phase A mapping (q=t>>4, c=t&15): f3dT gathers 256B-contiguous per point row.
// Phase B mapping (q=t&15, c=t>>4): out writes coalesced. LDS fin decouples.
__global__ __launch_bounds__(256) void k2_mlp(
    const int4* __restrict__ idx4, const float* __restrict__ uv,
    const float* __restrict__ f3dT,
    const float* __restrict__ w1, const float* __restrict__ b1,
    const float* __restrict__ w2, const float* __restrict__ b2,
    const float* __restrict__ w_out, const float* __restrict__ b_out,
    float* __restrict__ out) {
  int blk = blockIdx.x;            // group of 16 queries
  int b = blockIdx.y;
  int t = threadIdx.x;

  __shared__ float fin[16][68];    // row stride 272 B (16B-aligned)

  // ===== phase A: gather + score, 4 channels per thread =====
  {
    int qa = t >> 4;               // query slot 0..15
    int ca = t & 15;               // channel group 0..15 (4 ch each)
    int q = blk * 16 + qa;
    float xf = (float)(q % WW);
    float yf = (float)(q / WW);
    int4 id4 = idx4[(size_t)b * HW + q];
    int idx[3] = {id4.x, id4.y, id4.z};

    // h1 (redundant across the 16 channel groups; pure VALU)
    float h1a[3][16];
#pragma unroll
    for (int k = 0; k < 3; ++k) {
      int i = idx[k];
      float u0 = uv[(size_t)b * 2 * NPTS + i];
      float u1 = uv[(size_t)b * 2 * NPTS + NPTS + i];
      float dx = u0 - xf;
      float dy = u1 - yf;
      float nrm = sqrtf(dx * dx + dy * dy);
#pragma unroll
      for (int o = 0; o < 16; ++o) {
        float h = fmaf(w1[o * 3 + 0], dx,
                 fmaf(w1[o * 3 + 1], dy,
                 fmaf(w1[o * 3 + 2], nrm, b1[o])));
        h1a[k][o] = (h >= 0.0f) ? h : 0.1f * h;
      }
    }

    float4 f0 = *(const float4*)(f3dT + ((size_t)b * NPTS + idx[0]) * NC + ca * 4);
    float4 f1 = *(const float4*)(f3dT + ((size_t)b * NPTS + idx[1]) * NC + ca * 4);
    float4 f2 = *(const float4*)(f3dT + ((size_t)b * NPTS + idx[2]) * NC + ca * 4);
    float fa[4] = {f0.x, f0.y, f0.z, f0.w};
    float fb[4] = {f1.x, f1.y, f1.z, f1.w};
    float fc[4] = {f2.x, f2.y, f2.z, f2.w};
#pragma unroll
    for (int cc = 0; cc < 4; ++cc) {
      int c = ca * 4 + cc;
      float bias = b2[c];
      float s0 = bias, s1 = bias, s2 = bias;
      const float4* w2r = (const float4*)(w2 + c * 16);
#pragma unroll
      for (int o4 = 0; o4 < 4; ++o4) {
        float4 wv = w2r[o4];
        float wvs[4] = {wv.x, wv.y, wv.z, wv.w};
#pragma unroll
        for (int oo = 0; oo < 4; ++oo) {
          int o = o4 * 4 + oo;
          s0 = fmaf(wvs[oo], h1a[0][o], s0);
          s1 = fmaf(wvs[oo], h1a[1][o], s1);
          s2 = fmaf(wvs[oo], h1a[2][o], s2);
        }
      }
      float g0 = 1.0f / (1.0f + __expf(-s0));
      float g1 = 1.0f / (1.0f + __expf(-s1));
      float g2 = 1.0f / (1.0f + __expf(-s2));
      fin[qa][c] = fmaf(g0, fa[cc], fmaf(g1, fb[cc], g2 * fc[cc]));
    }
  }
  __syncthreads();

  // ===== phase B: out-projection, 4 output channels per thread =====
  {
    int qb = t & 15;
    int cgb = t >> 4;
    int q = blk * 16 + qb;
    int o0 = cgb * 4;
    float acc[4];
#pragma unroll
    for (int jj = 0; jj < 4; ++jj) acc[jj] = b_out[o0 + jj];
    const float4* finq = (const float4*)(&fin[qb][0]);
#pragma unroll 4
    for (int c4 = 0; c4 < 16; ++c4) {
      float4 f = finq[c4];
#pragma unroll
      for (int jj = 0; jj < 4; ++jj) {
        float4 wv = *(const float4*)(w_out + (o0 + jj) * 64 + c4 * 4);
        acc[jj] = fmaf(wv.x, f.x,
                  fmaf(wv.y, f.y,
                  fmaf(wv.z, f.z,
                  fmaf(wv.w, f.w, acc[jj]))));
      }
    }
    float* dst = out + ((size_t)(b * 64 + o0)) * HW + q;
#pragma unroll
    for (int jj = 0; jj < 4; ++jj) {
      float v = acc[jj];
      dst[(size_t)jj * HW] = (v >= 0.0f) ? v : 0.1f * v;
    }
  }
}

extern "C" void kernel_launch(void* const* d_in, const int* in_sizes, int n_in,
                              void* d_out, int out_size, void* d_ws, size_t ws_size,
                              hipStream_t stream) {
  const float* uv   = (const float*)d_in[0];
  // d_in[1] = feat_2d : values unused by the reference (shape only)
  const float* f3d  = (const float*)d_in[2];
  const float* w1   = (const float*)d_in[3];
  const float* b1   = (const float*)d_in[4];
  const float* w2   = (const float*)d_in[5];
  const float* b2   = (const float*)d_in[6];
  const float* wout = (const float*)d_in[7];
  const float* bout = (const float*)d_in[8];
  float* out = (float*)d_out;

  char* ws = (char*)d_ws;
  float*  f3dT      = (float*)(ws);             // 2*4096*64*4 = 2097152 B
  float4* binned    = (float4*)(ws + 2097152);  // 2*4096*16   = 131072 B
  int*    cellStart = (int*)(ws + 2228224);     // 2*200*4     = 1600 B
  int4*   idx4      = (int4*)(ws + 2232320);    // 2*12288*16  = 393216 B
                                                // total ≈ 2.63 MB

  hipLaunchKernelGGL(k0_prep, dim3(130), dim3(256), 0, stream,
                     uv, f3d, f3dT, binned, cellStart);
  hipLaunchKernelGGL(k1_knn, dim3(NCELL, NBS), dim3(128), 0, stream,
                     (const float4*)binned, (const int*)cellStart, idx4);
  hipLaunchKernelGGL(k2_mlp, dim3(HW / 16, NBS), dim3(256), 0, stream,
                     (const int4*)idx4, uv, f3dT, w1, b1, w2, b2, wout, bout, out);
}

// Round 11
// 48.110 us; speedup vs baseline: 1.3484x; 1.3484x over previous
//
#include <hip/hip_runtime.h>
#include <math.h>

#define NBS 2
#define NPTS 4096
#define HH 64
#define WW 192
#define HW (HH*WW)        // 12288
#define NC 64
#define GX 48             // cells in x (4 px each)
#define GY 16             // cells in y
#define NCELL (GX*GY)     // 768
#define CSB 1024          // cellStart stride per batch

#define FBIG 3.0e38f
#define IBIG 0x7FFFFFFF

// ---------------- K0: bin points (blocks 0-1) + transpose feat_3d -----------
__global__ __launch_bounds__(256) void k0_prep(
    const float* __restrict__ uv, const float* __restrict__ f3d,
    float* __restrict__ f3dT, float4* __restrict__ binned,
    int* __restrict__ cellStart) {
#pragma clang fp contract(off)
  int bid = blockIdx.x;
  int t = threadIdx.x;
  if (bid < 2) {
    // counting-sort bin for batch b (single block per batch)
    int b = bid;
    __shared__ int hist[NCELL];
    __shared__ int cum[NCELL];
    __shared__ int cur[NCELL];
    for (int c = t; c < NCELL; c += 256) hist[c] = 0;
    __syncthreads();
    const float* u0p = uv + (size_t)b * 2 * NPTS;
    const float* u1p = u0p + NPTS;
    for (int n = t; n < NPTS; n += 256) {
      float u0 = u0p[n], u1 = u1p[n];
      int cxp = min((int)(u0 * 0.25f), GX - 1);   // *0.25f exact (pow2)
      int cyp = min((int)(u1 * 0.25f), GY - 1);
      atomicAdd(&hist[cyp * GX + cxp], 1);
    }
    __syncthreads();
    // single-wave inclusive scan: 12 chunks of 64 + running carry
    if (t < 64) {
      int carry = 0;
#pragma unroll
      for (int ck = 0; ck < NCELL / 64; ++ck) {
        int v = hist[ck * 64 + t];
#pragma unroll
        for (int off = 1; off < 64; off <<= 1) {
          int u = __shfl_up(v, off);
          if (t >= off) v += u;
        }
        cum[ck * 64 + t] = v + carry;
        carry += __shfl(v, 63);
      }
    }
    __syncthreads();
    if (t == 0) cellStart[b * CSB] = 0;
    for (int c = t; c < NCELL; c += 256) {
      cellStart[b * CSB + c + 1] = cum[c];
      cur[c] = cum[c] - hist[c];            // exclusive start
    }
    __syncthreads();
    for (int n = t; n < NPTS; n += 256) {
      float u0 = u0p[n], u1 = u1p[n];
      // golden rounding: uu = rnd(rnd(u0^2)+rnd(u1^2)); contract(off) => no fma
      float s0 = u0 * u0;
      float s1 = u1 * u1;
      float uu = s0 + s1;
      int cxp = min((int)(u0 * 0.25f), GX - 1);
      int cyp = min((int)(u1 * 0.25f), GY - 1);
      int pos = atomicAdd(&cur[cyp * GX + cxp], 1);
      binned[(size_t)b * NPTS + pos] =
          make_float4(u0 + u0, u1 + u1, uu, __int_as_float(n));
    }
  } else {
    // transpose 64n x 32c half-tile: bb in [0,256)
    int bb = bid - 2;
    int b = bb >> 7;                       // batch
    int half = (bb >> 6) & 1;              // channel half
    int nt = (bb & 63) << 6;               // n tile base
    __shared__ float tile[32][65];
    int n_in = t & 63;
    int r0 = t >> 6;                       // 0..3
    const float* src = f3d + (size_t)b * NC * NPTS + (size_t)half * 32 * NPTS;
#pragma unroll
    for (int r = 0; r < 8; ++r) {
      int c = r0 + (r << 2);               // 0..31
      tile[c][n_in] = src[(size_t)c * NPTS + nt + n_in];
    }
    __syncthreads();
    float* dst = f3dT + ((size_t)b * NPTS + nt) * NC + half * 32;
    int c_out = t & 31;                    // 0..31
    int n0 = t >> 5;                       // 0..7
#pragma unroll
    for (int r = 0; r < 8; ++r) {
      int n = n0 + (r << 3);
      dst[(size_t)n * NC + c_out] = tile[c_out][n];
    }
  }
}

// ---------------- K_MAIN: fused binned 3-NN + MLP + out-projection ----------
// Block = 16 queries x 256 threads. Phase 1: KNN, 16 lanes/query, lex (d,idx)
// smallest-3, DUPLICATE-SAFE insert (repeat merges are idempotent — the R10
// ring-path corruption fix). Phase 1.5: coop h1. Phase 2: score+sum. B: proj.
__global__ __launch_bounds__(256) void k_main(
    const float4* __restrict__ binned, const int* __restrict__ cellStart,
    const float* __restrict__ uv, const float* __restrict__ f3dT,
    const float* __restrict__ w1, const float* __restrict__ b1,
    const float* __restrict__ w2, const float* __restrict__ b2,
    const float* __restrict__ w_out, const float* __restrict__ b_out,
    float* __restrict__ out) {
#pragma clang fp contract(off)
  int t = threadIdx.x;
  int b = blockIdx.y;

  __shared__ int sidx[16][4];
  __shared__ float sh1f[16 * 52];  // h1[3][16] per query, 52-float row
  __shared__ float fin[16][68];    // row stride 272 B

  // ===== phase 1: KNN =====
  {
    int Q = t >> 4;                      // query slot 0..15
    int j = t & 15;                      // splitter lane
    int qi = blockIdx.x * 16 + Q;
    int x = qi % WW, y = qi / WW;
    float xf = (float)x, yf = (float)y;
    float gg = xf * xf + yf * yf;        // exact small ints
    int cx = x >> 2, cy = y >> 2;

    const float4* __restrict__ pts = binned + (size_t)b * NPTS;
    const int* __restrict__ cs = cellStart + b * CSB;

    float v0 = FBIG, v1 = FBIG, v2 = FBIG;
    int i0 = IBIG, i1 = IBIG, i2 = IBIG;

    // duplicate-safe lex (d,idx) sorted insert: a candidate equal to an
    // already-held index is skipped (its (d,gi) pair is identical, so this
    // is exact). Makes repeated cross-lane merges idempotent.
    auto ins = [&](float d, int gi) {
      bool dup = (gi == i0) || (gi == i1) || (gi == i2);
      bool lt2 = !dup && ((d < v2) || (d == v2 && gi < i2));
      bool lt1 = !dup && ((d < v1) || (d == v1 && gi < i1));
      bool lt0 = !dup && ((d < v0) || (d == v0 && gi < i0));
      i2 = lt1 ? i1 : (lt2 ? gi : i2);
      v2 = lt1 ? v1 : (lt2 ? d : v2);
      i1 = lt0 ? i0 : (lt1 ? gi : i1);
      v1 = lt0 ? v0 : (lt1 ? d : v1);
      i0 = lt0 ? gi : i0;
      v0 = lt0 ? d : v0;
    };
    auto scanRow = [&](int ry, int cA, int cB) {
      int s = cs[ry * GX + cA];
      int e = cs[ry * GX + cB + 1];      // cells row-contiguous -> one segment
      for (int n = s + j; n < e; n += 16) {
        float4 p = pts[n];
        // golden: d2 = rnd(gg+uu) - 2*fma(y,u1, rnd(x*u0)); x2 pre-scaled
        float d = (gg + p.z) - __builtin_fmaf(yf, p.y, xf * p.x);
        ins(d, __float_as_int(p.w));
      }
    };
    auto mergeAll = [&]() {
#pragma unroll
      for (int m = 1; m <= 8; m <<= 1) {
        float ov0 = __shfl_xor(v0, m), ov1 = __shfl_xor(v1, m),
              ov2 = __shfl_xor(v2, m);
        int oi0 = __shfl_xor(i0, m), oi1 = __shfl_xor(i1, m),
            oi2 = __shfl_xor(i2, m);
        ins(ov0, oi0); ins(ov1, oi1); ins(ov2, oi2);
      }
    };

    int cxL = max(cx - 1, 0), cxH = min(cx + 1, GX - 1);
    int cyL = max(cy - 1, 0), cyH = min(cy + 1, GY - 1);
    for (int ry = cyL; ry <= cyH; ++ry) scanRow(ry, cxL, cxH);
    mergeAll();

    // ring expansion: rare (P ~ 8e-4/query at 4px cells) but exactness-
    // preserving. Computed-d2 skew bound <= 0.05 << 1.0 slack.
    while (true) {
      bool fullDom = (cxL == 0 && cxH == GX - 1 && cyL == 0 && cyH == GY - 1);
      float dL = (cxL > 0) ? (xf - (float)(cxL * 4)) : FBIG;
      float dR = (cxH < GX - 1) ? ((float)((cxH + 1) * 4) - xf) : FBIG;
      float dB = (cyL > 0) ? (yf - (float)(cyL * 4)) : FBIG;
      float dT = (cyH < GY - 1) ? ((float)((cyH + 1) * 4) - yf) : FBIG;
      float dmin = fminf(fminf(dL, dR), fminf(dB, dT));
      if (fullDom || (v2 < dmin * dmin - 1.0f)) break;
      int nxL = max(cxL - 1, 0), nxH = min(cxH + 1, GX - 1);
      int nyL = max(cyL - 1, 0), nyH = min(cyH + 1, GY - 1);
      for (int ry = nyL; ry <= nyH; ++ry) {
        if (ry < cyL || ry > cyH) scanRow(ry, nxL, nxH);
        else {
          if (nxL < cxL) scanRow(ry, nxL, cxL - 1);
          if (nxH > cxH) scanRow(ry, cxH + 1, nxH);
        }
      }
      cxL = nxL; cxH = nxH; cyL = nyL; cyH = nyH;
      mergeAll();
    }

    if (j == 0) { sidx[Q][0] = i0; sidx[Q][1] = i1; sidx[Q][2] = i2; }
  }
  __syncthreads();

  // ===== phase 1.5: cooperative h1 — lane o of query Q computes h1[k][o] ====
  {
    int Q = t >> 4;
    int o = t & 15;
    int qi = blockIdx.x * 16 + Q;
    float xf = (float)(qi % WW);
    float yf = (float)(qi / WW);
    float wa = w1[o * 3 + 0], wb = w1[o * 3 + 1], wc = w1[o * 3 + 2];
    float bo = b1[o];
#pragma unroll
    for (int k = 0; k < 3; ++k) {
      int i = sidx[Q][k];
      float u0 = uv[(size_t)b * 2 * NPTS + i];
      float u1 = uv[(size_t)b * 2 * NPTS + NPTS + i];
      float dx = u0 - xf;
      float dy = u1 - yf;
      float nrm = sqrtf(__builtin_fmaf(dx, dx, dy * dy));
      float h = fmaf(wa, dx, fmaf(wb, dy, fmaf(wc, nrm, bo)));
      sh1f[Q * 52 + k * 16 + o] = (h >= 0.0f) ? h : 0.1f * h;
    }
  }
  __syncthreads();

  // ===== phase 2: score + weighted feature sum (ql=t&15, cg=t>>4) ==========
  {
    int ql = t & 15;
    int cg = t >> 4;                 // channel group (4 ch)
    float h1a[3][16];
    {
      const float4* h4 = (const float4*)(sh1f + ql * 52);
#pragma unroll
      for (int i = 0; i < 12; ++i) {
        float4 v = h4[i];
        int k = i >> 2, oo = (i & 3) * 4;
        h1a[k][oo + 0] = v.x; h1a[k][oo + 1] = v.y;
        h1a[k][oo + 2] = v.z; h1a[k][oo + 3] = v.w;
      }
    }
    int idx[3] = {sidx[ql][0], sidx[ql][1], sidx[ql][2]};
    float4 f0 = *(const float4*)(f3dT + ((size_t)b * NPTS + idx[0]) * NC + cg * 4);
    float4 f1 = *(const float4*)(f3dT + ((size_t)b * NPTS + idx[1]) * NC + cg * 4);
    float4 f2 = *(const float4*)(f3dT + ((size_t)b * NPTS + idx[2]) * NC + cg * 4);
    float fa[4] = {f0.x, f0.y, f0.z, f0.w};
    float fb[4] = {f1.x, f1.y, f1.z, f1.w};
    float fc[4] = {f2.x, f2.y, f2.z, f2.w};
#pragma unroll
    for (int cc = 0; cc < 4; ++cc) {
      int c = cg * 4 + cc;
      float bias = b2[c];
      float s0 = bias, s1 = bias, s2 = bias;
      const float4* w2r = (const float4*)(w2 + c * 16);
#pragma unroll
      for (int o4 = 0; o4 < 4; ++o4) {
        float4 wv = w2r[o4];
        float wvs[4] = {wv.x, wv.y, wv.z, wv.w};
#pragma unroll
        for (int oo = 0; oo < 4; ++oo) {
          int o = o4 * 4 + oo;
          s0 = fmaf(wvs[oo], h1a[0][o], s0);
          s1 = fmaf(wvs[oo], h1a[1][o], s1);
          s2 = fmaf(wvs[oo], h1a[2][o], s2);
        }
      }
      float g0 = 1.0f / (1.0f + __expf(-s0));
      float g1 = 1.0f / (1.0f + __expf(-s1));
      float g2 = 1.0f / (1.0f + __expf(-s2));
      fin[ql][c] = fmaf(g0, fa[cc], fmaf(g1, fb[cc], g2 * fc[cc]));
    }
  }
  __syncthreads();

  // ===== phase B: out-projection, 4 output channels per thread =============
  {
    int qb = t & 15;
    int cgb = t >> 4;
    int q = blockIdx.x * 16 + qb;
    int o0 = cgb * 4;
    float acc[4];
#pragma unroll
    for (int jj = 0; jj < 4; ++jj) acc[jj] = b_out[o0 + jj];
    const float4* finq = (const float4*)(&fin[qb][0]);
#pragma unroll 4
    for (int c4 = 0; c4 < 16; ++c4) {
      float4 f = finq[c4];
#pragma unroll
      for (int jj = 0; jj < 4; ++jj) {
        float4 wv = *(const float4*)(w_out + (o0 + jj) * 64 + c4 * 4);
        acc[jj] = fmaf(wv.x, f.x,
                  fmaf(wv.y, f.y,
                  fmaf(wv.z, f.z,
                  fmaf(wv.w, f.w, acc[jj]))));
      }
    }
    float* dst = out + ((size_t)(b * 64 + o0)) * HW + q;
#pragma unroll
    for (int jj = 0; jj < 4; ++jj) {
      float v = acc[jj];
      dst[(size_t)jj * HW] = (v >= 0.0f) ? v : 0.1f * v;
    }
  }
}

extern "C" void kernel_launch(void* const* d_in, const int* in_sizes, int n_in,
                              void* d_out, int out_size, void* d_ws, size_t ws_size,
                              hipStream_t stream) {
  const float* uv   = (const float*)d_in[0];
  // d_in[1] = feat_2d : values unused by the reference (shape only)
  const float* f3d  = (const float*)d_in[2];
  const float* w1   = (const float*)d_in[3];
  const float* b1   = (const float*)d_in[4];
  const float* w2   = (const float*)d_in[5];
  const float* b2   = (const float*)d_in[6];
  const float* wout = (const float*)d_in[7];
  const float* bout = (const float*)d_in[8];
  float* out = (float*)d_out;

  char* ws = (char*)d_ws;
  float*  f3dT      = (float*)(ws);             // 2*4096*64*4 = 2097152 B
  float4* binned    = (float4*)(ws + 2097152);  // 2*4096*16   = 131072 B
  int*    cellStart = (int*)(ws + 2228224);     // 2*1024*4    = 8192 B
                                                // total ≈ 2.24 MB

  hipLaunchKernelGGL(k0_prep, dim3(258), dim3(256), 0, stream,
                     uv, f3d, f3dT, binned, cellStart);
  hipLaunchKernelGGL(k_main, dim3(HW / 16, NBS), dim3(256), 0, stream,
                     (const float4*)binned, (const int*)cellStart,
                     uv, f3dT, w1, b1, w2, b2, wout, bout, out);
}